// Round 7
// baseline (73.191 us; speedup 1.0000x reference)
//
#include <hip/hip_runtime.h>
#include <hip/hip_bf16.h>

typedef __bf16 bf16x8 __attribute__((ext_vector_type(8)));
typedef float f32x4 __attribute__((ext_vector_type(4)));

#define NB 8
#define NH 128
#define NWID 128
#define NC 32
#define NO 32
#define NPTS 9
// KPAD 776 does double duty:
//  (a) bank structure: row stride 388 words == 4 mod 32 -> rows 0-7 tile all
//      32 banks, rows 8-15 are the free 2-way alias (m136).
//  (b) occupancy governor: sW = 32*776*2B = 49.7KB -> 3 blocks/CU cap, so
//      regalloc targets 3 waves/EU and gives the depth-2 pipeline ~170 VGPRs
//      instead of squeezing to 60 (the R3-R6 serialization bug).
#define KPAD 776
#define PB 64         // pixels per block (4 waves x 16)

__global__ __launch_bounds__(256, 2)
void dcn_kernel(const float* __restrict__ x,
                const float* __restrict__ off,
                const float* __restrict__ Wsrc,
                const float* __restrict__ bias,
                float* __restrict__ out)
{
    __shared__ __hip_bfloat16 sW[NO][KPAD];

    const int tid = threadIdx.x;

    // ---- stage W (identity layout, R4-verified): W[n][c][o] -> sW[o][n*32+c] ----
    for (int idx = tid; idx < NPTS * NC * NO; idx += 256) {
        int n = idx >> 10;        // /(NC*NO)
        int r = idx & 1023;
        int c = r >> 5;
        int o = r & 31;
        sW[o][(n << 5) + c] = __float2bfloat16(Wsrc[idx]);
    }
    __syncthreads();

    // XCD swizzle: grid 2048 = 8 XCDs x 256 blocks; 256 blocks == one image
    // (2.1 MB < 4 MiB L2) -> gathers L2-resident per XCD. (R4: FETCH 110->13MB)
    const int lb = ((blockIdx.x & 7) << 8) | (blockIdx.x >> 3);
    const int pix0 = lb * PB;

    const int wave = tid >> 6;
    const int lane = tid & 63;
    const int row  = lane & 15;   // pixel within wave tile == A-frag row == B col
    const int cq   = lane >> 4;   // channel quad: channels 8cq..8cq+7
    const int gp   = pix0 + (wave << 4) + row;
    const int bidx = gp >> 14;
    const int hh   = (gp >> 7) & 127;
    const int ww   = gp & 127;
    const float* xb = x + ((size_t)bidx << 19);
    const float* xc = xb + (cq << 3);             // channel base (R4-verified)
    const float* offp = off + (size_t)gp * 18;

    // TF-quirk init_off: stack([ii,jj]).reshape(-1,2) pairs ACROSS the ii/jj boundary
    const int ioff0[9] = {0,0,1,2,2,1,0,2,1};
    const int ioff1[9] = {0,1,1,2,0,2,1,0,2};

    float2 ov[9];
    #pragma unroll
    for (int n = 0; n < 9; ++n)
        ov[n] = *reinterpret_cast<const float2*>(offp + 2 * n);

    f32x4 acc0 = {0.f, 0.f, 0.f, 0.f};
    f32x4 acc1 = {0.f, 0.f, 0.f, 0.f};

    // depth-2 software pipeline over the 9 points:
    // slot layout: [lt_a, lt_b, rt_a, rt_b, lb_a, lb_b, rb_a, rb_b]
    f32x4 L[2][8];
    float ff0[2], ff1[2];

#define ISSUE(S, N) {                                                          \
        float c0 = fminf(fmaxf((float)(hh - 1 + ioff0[N]) + ov[N].x, 0.f), 127.f); \
        float c1 = fminf(fmaxf((float)(ww - 1 + ioff1[N]) + ov[N].y, 0.f), 127.f); \
        float fl0 = floorf(c0), fl1 = floorf(c1);                              \
        int lt0 = (int)fl0, lt1 = (int)fl1;                                    \
        int rb0 = (int)ceilf(c0), rb1 = (int)ceilf(c1);                        \
        ff0[S] = c0 - fl0; ff1[S] = c1 - fl1;                                  \
        const float* p_lt = xc + ((((lt0 << 7) + lt1)) << 5);                  \
        const float* p_rt = xc + ((((rb0 << 7) + lt1)) << 5);                  \
        const float* p_lb = xc + ((((lt0 << 7) + rb1)) << 5);                  \
        const float* p_rb = xc + ((((rb0 << 7) + rb1)) << 5);                  \
        L[S][0] = *(const f32x4*)p_lt; L[S][1] = *(const f32x4*)(p_lt + 4);    \
        L[S][2] = *(const f32x4*)p_rt; L[S][3] = *(const f32x4*)(p_rt + 4);    \
        L[S][4] = *(const f32x4*)p_lb; L[S][5] = *(const f32x4*)(p_lb + 4);    \
        L[S][6] = *(const f32x4*)p_rb; L[S][7] = *(const f32x4*)(p_rb + 4);    \
    }

#define CONSUME(S, N) {                                                        \
        float f0 = ff0[S], f1 = ff1[S];                                        \
        union { bf16x8 v; __hip_bfloat16 h[8]; } au;                           \
        _Pragma("unroll")                                                      \
        for (int j = 0; j < 4; ++j) {                                          \
            float t = L[S][0][j] + (L[S][2][j] - L[S][0][j]) * f0;             \
            float b = L[S][4][j] + (L[S][6][j] - L[S][4][j]) * f0;             \
            au.h[j] = __float2bfloat16(t + (b - t) * f1);                      \
        }                                                                      \
        _Pragma("unroll")                                                      \
        for (int j = 0; j < 4; ++j) {                                          \
            float t = L[S][1][j] + (L[S][3][j] - L[S][1][j]) * f0;             \
            float b = L[S][5][j] + (L[S][7][j] - L[S][5][j]) * f0;             \
            au.h[4 + j] = __float2bfloat16(t + (b - t) * f1);                  \
        }                                                                      \
        const int kk = ((N) << 5) + (cq << 3);                                 \
        bf16x8 b0 = *reinterpret_cast<const bf16x8*>(&sW[row][kk]);            \
        bf16x8 b1 = *reinterpret_cast<const bf16x8*>(&sW[row + 16][kk]);       \
        acc0 = __builtin_amdgcn_mfma_f32_16x16x32_bf16(au.v, b0, acc0, 0, 0, 0); \
        acc1 = __builtin_amdgcn_mfma_f32_16x16x32_bf16(au.v, b1, acc1, 0, 0, 0); \
    }

    ISSUE(0, 0)
    #pragma unroll
    for (int n = 0; n < 9; ++n) {
        if (n < 8) ISSUE((n + 1) & 1, n + 1)
        // pin: next point's 8 loads must stay issued ABOVE this point's consume
        __builtin_amdgcn_sched_barrier(0);
        CONSUME(n & 1, n)
    }
#undef ISSUE
#undef CONSUME

    // ---- epilogue: C/D layout col=lane&15, row=(lane>>4)*4+i (R4-verified) ----
    const float bias0 = bias[row];
    const float bias1 = bias[row + 16];
    const int rbase = (wave << 4) + (cq << 2);
    #pragma unroll
    for (int i = 0; i < 4; ++i) {
        float* op = out + (size_t)(pix0 + rbase + i) * NO;
        op[row]      = acc0[i] + bias0;
        op[row + 16] = acc1[i] + bias1;
    }
}

extern "C" void kernel_launch(void* const* d_in, const int* in_sizes, int n_in,
                              void* d_out, int out_size, void* d_ws, size_t ws_size,
                              hipStream_t stream) {
    const float* x    = (const float*)d_in[0];
    const float* off  = (const float*)d_in[1];
    const float* Wsrc = (const float*)d_in[2];
    const float* bias = (const float*)d_in[3];
    float* out = (float*)d_out;
    const int npix = NB * NH * NWID;          // 131072
    dcn_kernel<<<npix / PB, 256, 0, stream>>>(x, off, Wsrc, bias, out);
}

// Round 8
// 72.808 us; speedup vs baseline: 1.0053x; 1.0053x over previous
//
#include <hip/hip_runtime.h>
#include <hip/hip_bf16.h>

typedef __bf16 bf16x8 __attribute__((ext_vector_type(8)));
typedef float f32x4 __attribute__((ext_vector_type(4)));

#define NB 8
#define NH 128
#define NWID 128
#define NC 32
#define NO 32
#define NPTS 9
#define KPAD 296      // sW row stride in halves (R2/R4-verified bank layout)
#define PB 64         // pixels per block (4 waves x 16)

__global__ __launch_bounds__(256, 2)
void dcn_kernel(const float* __restrict__ x,
                const float* __restrict__ off,
                const float* __restrict__ Wsrc,
                const float* __restrict__ bias,
                float* __restrict__ out)
{
    __shared__ __hip_bfloat16 sW[NO][KPAD];

    const int tid = threadIdx.x;

    // ---- stage W (identity layout, R4-verified): W[n][c][o] -> sW[o][n*32+c] ----
    for (int idx = tid; idx < NPTS * NC * NO; idx += 256) {
        int n = idx >> 10;
        int r = idx & 1023;
        int c = r >> 5;
        int o = r & 31;
        sW[o][(n << 5) + c] = __float2bfloat16(Wsrc[idx]);
    }
    __syncthreads();

    // XCD swizzle (R4: FETCH 110->13MB): one image per XCD, L2-resident.
    const int lb = ((blockIdx.x & 7) << 8) | (blockIdx.x >> 3);
    const int pix0 = lb * PB;

    const int wave = tid >> 6;
    const int lane = tid & 63;
    const int row  = lane & 15;   // pixel within wave tile == A-frag row == B col
    const int cq   = lane >> 4;   // channel quad: channels 8cq..8cq+7
    const int gp   = pix0 + (wave << 4) + row;
    const int bidx = gp >> 14;    // uniform per wave (16 consecutive px, one image)
    const int hh   = (gp >> 7) & 127;
    const int ww   = gp & 127;
    const float* xb = x + ((size_t)bidx << 19);   // wave-uniform image base
    const int cqb  = cq << 5;                     // cq*8 floats = 32 bytes
    const float* offp = off + (size_t)gp * 18;

    // TF-quirk init_off (R2-verified): pairs formed ACROSS the ii/jj boundary
    const int ioff0[9] = {0,0,1,2,2,1,0,2,1};
    const int ioff1[9] = {0,1,1,2,0,2,1,0,2};

    // ---- precompute ALL corner byte-voffsets + fracs (no normal vmem loads
    //      remain pending inside the asm pipeline -> compiler's waitcnt pass
    //      cannot insert a draining vmcnt(0) there) ----
    int vo_lt[9], vo_rt[9], vo_lb[9], vo_rb[9];
    float pf0[9], pf1[9];
    #pragma unroll
    for (int n = 0; n < 9; ++n) {
        float2 ovn = *reinterpret_cast<const float2*>(offp + 2 * n);
        float c0 = fminf(fmaxf((float)(hh - 1 + ioff0[n]) + ovn.x, 0.f), 127.f);
        float c1 = fminf(fmaxf((float)(ww - 1 + ioff1[n]) + ovn.y, 0.f), 127.f);
        float fl0 = floorf(c0), fl1 = floorf(c1);
        int lt0 = (int)fl0, lt1 = (int)fl1;
        int rb0 = (int)ceilf(c0), rb1 = (int)ceilf(c1);
        pf0[n] = c0 - fl0;
        pf1[n] = c1 - fl1;
        // byte offset: pixel_index*128B + cq*32B
        vo_lt[n] = (((lt0 << 7) + lt1) << 7) + cqb;
        vo_rt[n] = (((rb0 << 7) + lt1) << 7) + cqb;
        vo_lb[n] = (((lt0 << 7) + rb1) << 7) + cqb;
        vo_rb[n] = (((rb0 << 7) + rb1) << 7) + cqb;
    }

    f32x4 acc0 = {0.f, 0.f, 0.f, 0.f};
    f32x4 acc1 = {0.f, 0.f, 0.f, 0.f};

    // depth-2 asm pipeline: D[slot][lt_a,lt_b,rt_a,rt_b,lb_a,lb_b,rb_a,rb_b]
    f32x4 D[2][8];

#define GLD0(dst, vof) asm volatile("global_load_dwordx4 %0, %1, %2" \
        : "=v"(dst) : "v"(vof), "s"(xb));
#define GLD1(dst, vof) asm volatile("global_load_dwordx4 %0, %1, %2 offset:16" \
        : "=v"(dst) : "v"(vof), "s"(xb));

#define ISSUE(S, N) \
        GLD0(D[S][0], vo_lt[N]) GLD1(D[S][1], vo_lt[N]) \
        GLD0(D[S][2], vo_rt[N]) GLD1(D[S][3], vo_rt[N]) \
        GLD0(D[S][4], vo_lb[N]) GLD1(D[S][5], vo_lb[N]) \
        GLD0(D[S][6], vo_rb[N]) GLD1(D[S][7], vo_rb[N])

#define CONSUME(S, N) {                                                        \
        float f0 = pf0[N], f1 = pf1[N];                                        \
        union { bf16x8 v; __hip_bfloat16 h[8]; } au;                           \
        _Pragma("unroll")                                                      \
        for (int j = 0; j < 4; ++j) {                                          \
            float t = D[S][0][j] + (D[S][2][j] - D[S][0][j]) * f0;             \
            float b = D[S][4][j] + (D[S][6][j] - D[S][4][j]) * f0;             \
            au.h[j] = __float2bfloat16(t + (b - t) * f1);                      \
        }                                                                      \
        _Pragma("unroll")                                                      \
        for (int j = 0; j < 4; ++j) {                                          \
            float t = D[S][1][j] + (D[S][3][j] - D[S][1][j]) * f0;             \
            float b = D[S][5][j] + (D[S][7][j] - D[S][5][j]) * f0;             \
            au.h[4 + j] = __float2bfloat16(t + (b - t) * f1);                  \
        }                                                                      \
        const int kk = ((N) << 5) + (cq << 3);                                 \
        bf16x8 b0 = *reinterpret_cast<const bf16x8*>(&sW[row][kk]);            \
        bf16x8 b1 = *reinterpret_cast<const bf16x8*>(&sW[row + 16][kk]);       \
        acc0 = __builtin_amdgcn_mfma_f32_16x16x32_bf16(au.v, b0, acc0, 0, 0, 0); \
        acc1 = __builtin_amdgcn_mfma_f32_16x16x32_bf16(au.v, b1, acc1, 0, 0, 0); \
    }

    ISSUE(0, 0)
    ISSUE(1, 1)
    #pragma unroll
    for (int n = 0; n < 9; ++n) {
        // FIFO: outstanding = pt n (8) + pt n+1 (8); vmcnt(8) -> pt n complete,
        // pt n+1 stays in flight. Never drain to 0 mid-loop (T4 discipline).
        if (n < 8) { asm volatile("s_waitcnt vmcnt(8)" ::: "memory"); }
        else       { asm volatile("s_waitcnt vmcnt(0)" ::: "memory"); }
        __builtin_amdgcn_sched_barrier(0);   // rule #18: pin consumers below waitcnt
        CONSUME(n & 1, n)
        if (n < 7) { ISSUE(n & 1, n + 2) }   // refill the slot just consumed
    }
#undef ISSUE
#undef CONSUME
#undef GLD0
#undef GLD1

    // ---- epilogue: C/D layout col=lane&15, row=(lane>>4)*4+i (R4-verified) ----
    const float bias0 = bias[row];
    const float bias1 = bias[row + 16];
    const int rbase = (wave << 4) + (cq << 2);
    #pragma unroll
    for (int i = 0; i < 4; ++i) {
        float* op = out + (size_t)(pix0 + rbase + i) * NO;
        op[row]      = acc0[i] + bias0;
        op[row + 16] = acc1[i] + bias1;
    }
}

extern "C" void kernel_launch(void* const* d_in, const int* in_sizes, int n_in,
                              void* d_out, int out_size, void* d_ws, size_t ws_size,
                              hipStream_t stream) {
    const float* x    = (const float*)d_in[0];
    const float* off  = (const float*)d_in[1];
    const float* Wsrc = (const float*)d_in[2];
    const float* bias = (const float*)d_in[3];
    float* out = (float*)d_out;
    const int npix = NB * NH * NWID;          // 131072
    dcn_kernel<<<npix / PB, 256, 0, stream>>>(x, off, Wsrc, bias, out);
}